// Round 5
// baseline (786.166 us; speedup 1.0000x reference)
//
#include <hip/hip_runtime.h>

#define N_NODES 30000
#define N_EDGES 240000
#define NF 32
#define EF 16
#define HF 64
#define NC 8
#define NWG 1024
#define TPB 256
#define MAXE 320   // edges/WG <= 235 + maxdeg(~30); 320 is safe

// wbuf layout (float offsets)
#define W_COMB 0      // [16][16] We @ Wem[64:128)
#define B_COMB 256    // [16]     bem + be@Wem[64:128)
#define W_NC   272    // [16][32] We @ Wnm[0:64)
#define B_VEC  784    // [32]     be @ Wnm[0:64)
#define W_SD   816    // [32][32] cols 0-15: Wn@Wem[0:64) ; cols 16-31: Wn@Wem[128:192)
#define W_NB   1840   // [32][32] Wn @ Wnm[64:128)   (== W_SD + 1024)
#define B_SD   2864   // [32]     [bn@WemS | bn@WemD]
#define B_NB   2896   // [32]     bnm + bn@Wnm[64:128)  (== B_SD + 32)
#define W_NF   2928   // [32][8]  Wn @ Wfc
#define B_NF   3184   // [8]      bfc + bn@Wfc
#define WBUF_N 3192

__device__ __forceinline__ float sigmoidf_(float x) {
  return 1.0f / (1.0f + __expf(-x));
}

// ---------------------------------------------------------------------------
__global__ void __launch_bounds__(256) hist_kernel(
    const int* __restrict__ dst, int* __restrict__ cnt) {
  int e = blockIdx.x * 256 + threadIdx.x;
  if (e < N_EDGES) atomicAdd(&cnt[dst[e]], 1);
}

// exclusive scan of cnt[30000] -> off[30001], cursor = copy of off
__global__ void __launch_bounds__(1024) scan_kernel(
    const int* __restrict__ cnt, int* __restrict__ off, int* __restrict__ cursor) {
  __shared__ int part[1024];
  int t = threadIdx.x;
  const int CH = (N_NODES + 1023) / 1024;   // 30
  int base = t * CH;
  int lc[CH];
  int sum = 0;
  for (int i = 0; i < CH; ++i) {
    int idx = base + i;
    lc[i] = (idx < N_NODES) ? cnt[idx] : 0;
    sum += lc[i];
  }
  part[t] = sum;
  __syncthreads();
  for (int ofs = 1; ofs < 1024; ofs <<= 1) {
    int v = (t >= ofs) ? part[t - ofs] : 0;
    __syncthreads();
    part[t] += v;
    __syncthreads();
  }
  int run = (t == 0) ? 0 : part[t - 1];
  for (int i = 0; i < CH; ++i) {
    int idx = base + i;
    if (idx < N_NODES) {
      off[idx] = run;
      cursor[idx] = run;
      run += lc[i];
    }
  }
  if (t == 1023) off[N_NODES] = part[1023];
}

__global__ void __launch_bounds__(256) scatter_kernel(
    const float* __restrict__ edge_feat, const int* __restrict__ src,
    const int* __restrict__ dst, int* __restrict__ cursor,
    unsigned short* __restrict__ src_s, unsigned short* __restrict__ dst_s,
    float* __restrict__ e_buf) {
  int e = blockIdx.x * 256 + threadIdx.x;
  if (e >= N_EDGES) return;
  int d = dst[e];
  int pos = atomicAdd(&cursor[d], 1);
  src_s[pos] = (unsigned short)src[e];
  dst_s[pos] = (unsigned short)d;
  const float4* ep = (const float4*)(edge_feat + (size_t)e * EF);
  float4* op = (float4*)(e_buf + (size_t)pos * EF);
  op[0] = ep[0]; op[1] = ep[1]; op[2] = ep[2]; op[3] = ep[3];
}

// bnd[w] = smallest n with off[n] >= w*E/NWG ; bnd[NWG] = N
__global__ void __launch_bounds__(1024) partition_kernel(
    const int* __restrict__ off, int* __restrict__ bnd) {
  for (int w = threadIdx.x; w <= NWG; w += 1024) {
    if (w == NWG) { bnd[w] = N_NODES; continue; }
    long long target = ((long long)w * N_EDGES) / NWG;
    int lo = 0, hi = N_NODES;
    while (lo < hi) {
      int mid = (lo + hi) >> 1;
      if ((long long)off[mid] < target) lo = mid + 1; else hi = mid;
    }
    bnd[w] = lo;
  }
}

// ---------------------------------------------------------------------------
__global__ void __launch_bounds__(256) precompute_kernel(
    const float* __restrict__ Wn, const float* __restrict__ bn,
    const float* __restrict__ We, const float* __restrict__ be,
    const float* __restrict__ Wem, const float* __restrict__ bem,
    const float* __restrict__ Wnm, const float* __restrict__ bnm,
    const float* __restrict__ Wfc, const float* __restrict__ bfc,
    float* __restrict__ wbuf) {
  int tid = threadIdx.x;
  {  // Wcomb
    int r = tid >> 4, c = tid & 15;
    float acc = 0.f;
    for (int j = 0; j < HF; ++j) acc = fmaf(We[r * HF + j], Wem[(HF + j) * EF + c], acc);
    wbuf[W_COMB + tid] = acc;
  }
  for (int idx = tid; idx < EF * NF; idx += 256) {  // Wnc
    int r = idx >> 5, c = idx & 31;
    float acc = 0.f;
    for (int j = 0; j < HF; ++j) acc = fmaf(We[r * HF + j], Wnm[j * NF + c], acc);
    wbuf[W_NC + idx] = acc;
  }
  for (int idx = tid; idx < NF * NF; idx += 256) {  // WSD
    int r = idx >> 5, c = idx & 31;
    float acc = 0.f;
    if (c < EF) {
      for (int j = 0; j < HF; ++j) acc = fmaf(Wn[r * HF + j], Wem[j * EF + c], acc);
    } else {
      int cc = c - EF;
      for (int j = 0; j < HF; ++j) acc = fmaf(Wn[r * HF + j], Wem[(2 * HF + j) * EF + cc], acc);
    }
    wbuf[W_SD + idx] = acc;
  }
  for (int idx = tid; idx < NF * NF; idx += 256) {  // WnB
    int r = idx >> 5, c = idx & 31;
    float acc = 0.f;
    for (int j = 0; j < HF; ++j) acc = fmaf(Wn[r * HF + j], Wnm[(HF + j) * NF + c], acc);
    wbuf[W_NB + idx] = acc;
  }
  if (tid < NF * NC) {  // Wnf
    int r = tid >> 3, c = tid & 7;
    float acc = 0.f;
    for (int j = 0; j < HF; ++j) acc = fmaf(Wn[r * HF + j], Wfc[j * NC + c], acc);
    wbuf[W_NF + tid] = acc;
  }
  if (tid < EF) {  // bcomb
    float acc = bem[tid];
    for (int j = 0; j < HF; ++j) acc = fmaf(be[j], Wem[(HF + j) * EF + tid], acc);
    wbuf[B_COMB + tid] = acc;
  }
  if (tid < NF) {  // bvec
    float acc = 0.f;
    for (int j = 0; j < HF; ++j) acc = fmaf(be[j], Wnm[j * NF + tid], acc);
    wbuf[B_VEC + tid] = acc;
  }
  if (tid < NF) {  // bSD
    float acc = 0.f;
    if (tid < EF) {
      for (int j = 0; j < HF; ++j) acc = fmaf(bn[j], Wem[j * EF + tid], acc);
    } else {
      int cc = tid - EF;
      for (int j = 0; j < HF; ++j) acc = fmaf(bn[j], Wem[(2 * HF + j) * EF + cc], acc);
    }
    wbuf[B_SD + tid] = acc;
  }
  if (tid < NF) {  // bNB
    float acc = bnm[tid];
    for (int j = 0; j < HF; ++j) acc = fmaf(bn[j], Wnm[(HF + j) * NF + tid], acc);
    wbuf[B_NB + tid] = acc;
  }
  if (tid < NC) {  // bnf
    float acc = bfc[tid];
    for (int j = 0; j < HF; ++j) acc = fmaf(bn[j], Wfc[j * NC + tid], acc);
    wbuf[B_NF + tid] = acc;
  }
}

// ---------------------------------------------------------------------------
// init: [P_s|P_d] = x@WSD + bSD (p=0) ; hpart = x@WnB + bNB (p=1)
// ---------------------------------------------------------------------------
__global__ void __launch_bounds__(256) init_proj_kernel(
    const float* __restrict__ node_feat, const float* __restrict__ wbuf,
    float* __restrict__ Ps, float* __restrict__ Pd, float* __restrict__ hpart) {
  __shared__ float sPRJ[2048];
  __shared__ float sPB[64];
  for (int i = threadIdx.x; i < 2048; i += 256) sPRJ[i] = wbuf[W_SD + i];
  if (threadIdx.x < 64) sPB[threadIdx.x] = wbuf[B_SD + threadIdx.x];
  __syncthreads();
  int gid = blockIdx.x * 256 + threadIdx.x;
  int n = gid >> 1, p = gid & 1;
  if (n >= N_NODES) return;
  float x[NF];
  const float4* xp = (const float4*)(node_feat + (size_t)n * NF);
#pragma unroll
  for (int k4 = 0; k4 < 8; ++k4) {
    float4 v = xp[k4];
    x[4 * k4] = v.x; x[4 * k4 + 1] = v.y; x[4 * k4 + 2] = v.z; x[4 * k4 + 3] = v.w;
  }
  float pr[NF];
  const float* pb = sPB + p * 32;
#pragma unroll
  for (int j = 0; j < NF; ++j) pr[j] = pb[j];
  const float* wbase = sPRJ + p * 1024;
  for (int k = 0; k < NF; ++k) {
    float v = x[k];
    const float4* wr = (const float4*)(wbase + k * NF);
#pragma unroll
    for (int j4 = 0; j4 < 8; ++j4) {
      float4 w = wr[j4];
      pr[4 * j4 + 0] = fmaf(v, w.x, pr[4 * j4 + 0]);
      pr[4 * j4 + 1] = fmaf(v, w.y, pr[4 * j4 + 1]);
      pr[4 * j4 + 2] = fmaf(v, w.z, pr[4 * j4 + 2]);
      pr[4 * j4 + 3] = fmaf(v, w.w, pr[4 * j4 + 3]);
    }
  }
  if (p == 0) {
    float4* a = (float4*)(Ps + (size_t)n * EF);
    a[0] = make_float4(pr[0], pr[1], pr[2], pr[3]);
    a[1] = make_float4(pr[4], pr[5], pr[6], pr[7]);
    a[2] = make_float4(pr[8], pr[9], pr[10], pr[11]);
    a[3] = make_float4(pr[12], pr[13], pr[14], pr[15]);
    float4* b = (float4*)(Pd + (size_t)n * EF);
    b[0] = make_float4(pr[16], pr[17], pr[18], pr[19]);
    b[1] = make_float4(pr[20], pr[21], pr[22], pr[23]);
    b[2] = make_float4(pr[24], pr[25], pr[26], pr[27]);
    b[3] = make_float4(pr[28], pr[29], pr[30], pr[31]);
  } else {
    float4* h = (float4*)(hpart + (size_t)n * NF);
#pragma unroll
    for (int j4 = 0; j4 < 8; ++j4)
      h[j4] = make_float4(pr[4 * j4], pr[4 * j4 + 1], pr[4 * j4 + 2], pr[4 * j4 + 3]);
  }
}

// ---------------------------------------------------------------------------
// One fused iteration (i = 1..10): WG w owns nodes [bnd[w],bnd[w+1]) and
// their dst-sorted edges. Stage e-slice to LDS; seg-sum from LDS (state i);
// edge update writes new e straight to global (in place — own slice only);
// node update reads hpart(i), writes PsW/PdW = proj(h_n(i+1)) + hpart(i+1).
// Cross-WG visibility is provided by the kernel boundary — no atomics.
// ---------------------------------------------------------------------------
__global__ void __launch_bounds__(TPB, 2) iter_kernel(
    float* __restrict__ e_buf,
    const unsigned short* __restrict__ src_s,
    const unsigned short* __restrict__ dst_s,
    const int* __restrict__ off, const int* __restrict__ bnd,
    const float* __restrict__ wbuf, float* __restrict__ hpart,
    const float* __restrict__ PsR, const float* __restrict__ PdR,
    float* __restrict__ PsW, float* __restrict__ PdW) {
  __shared__ float sE[MAXE * EF];           // 20 KB
  __shared__ float sW[WBUF_N];              // 12.8 KB
  __shared__ unsigned short sSrc[MAXE];
  __shared__ unsigned short sDst[MAXE];
  const int tid = threadIdx.x, w = blockIdx.x;
  const int nstart = bnd[w], nend = bnd[w + 1];
  const int estart = off[nstart];
  const int eloc = off[nend] - estart;
  const int nloc = nend - nstart;

  for (int i = tid; i < WBUF_N; i += TPB) sW[i] = wbuf[i];
  {
    const float4* g4 = (const float4*)(e_buf + (size_t)estart * EF);
    float4* l4 = (float4*)sE;
    for (int i = tid; i < eloc * 4; i += TPB) l4[i] = g4[i];
    for (int i = tid; i < eloc; i += TPB) {
      sSrc[i] = src_s[estart + i];
      sDst[i] = dst_s[estart + i];
    }
  }
  const int ln = tid >> 1, p = tid & 1;
  const int n = nstart + ln;
  const bool active = (ln < nloc);
  int eo0 = 0, eo1 = 0;
  if (active) { eo0 = off[n] - estart; eo1 = off[n + 1] - estart; }
  __syncthreads();

  // seg: per-pair sum of this node's edges (state i), 8 comps per lane
  float s8[8] = {0, 0, 0, 0, 0, 0, 0, 0};
  if (active) {
    for (int q = eo0; q < eo1; ++q) {
      const float4* ep = (const float4*)(sE + q * EF + 8 * p);
      float4 a = ep[0], b = ep[1];
      s8[0] += a.x; s8[1] += a.y; s8[2] += a.z; s8[3] += a.w;
      s8[4] += b.x; s8[5] += b.y; s8[6] += b.z; s8[7] += b.w;
    }
  }

  // edge phase: e' = sigmoid(bcomb + e@Wcomb + Ps[src] + Pd[dst]) -> global
  for (int q = tid; q < eloc; q += TPB) {
    int s = sSrc[q], d = sDst[q];
    const float4* ps = (const float4*)(PsR + (size_t)s * EF);
    const float4* pd = (const float4*)(PdR + (size_t)d * EF);
    float z[EF];
#pragma unroll
    for (int i4 = 0; i4 < 4; ++i4) {
      float4 a = ps[i4], b = pd[i4];
      z[4 * i4 + 0] = sW[B_COMB + 4 * i4 + 0] + a.x + b.x;
      z[4 * i4 + 1] = sW[B_COMB + 4 * i4 + 1] + a.y + b.y;
      z[4 * i4 + 2] = sW[B_COMB + 4 * i4 + 2] + a.z + b.z;
      z[4 * i4 + 3] = sW[B_COMB + 4 * i4 + 3] + a.w + b.w;
    }
    const float4* ebp = (const float4*)(sE + q * EF);
#pragma unroll
    for (int k4 = 0; k4 < 4; ++k4) {
      float4 ev = ebp[k4];
      float evv[4] = {ev.x, ev.y, ev.z, ev.w};
#pragma unroll
      for (int t = 0; t < 4; ++t) {
        float v = evv[t];
        const float4* wr = (const float4*)(sW + W_COMB + (4 * k4 + t) * EF);
#pragma unroll
        for (int i4 = 0; i4 < 4; ++i4) {
          float4 wv = wr[i4];
          z[4 * i4 + 0] = fmaf(v, wv.x, z[4 * i4 + 0]);
          z[4 * i4 + 1] = fmaf(v, wv.y, z[4 * i4 + 1]);
          z[4 * i4 + 2] = fmaf(v, wv.z, z[4 * i4 + 2]);
          z[4 * i4 + 3] = fmaf(v, wv.w, z[4 * i4 + 3]);
        }
      }
    }
#pragma unroll
    for (int i = 0; i < EF; ++i) z[i] = sigmoidf_(z[i]);
    float4* og = (float4*)(e_buf + (size_t)(estart + q) * EF);
#pragma unroll
    for (int i4 = 0; i4 < 4; ++i4)
      og[i4] = make_float4(z[4 * i4], z[4 * i4 + 1], z[4 * i4 + 2], z[4 * i4 + 3]);
  }

  // node phase
  if (active) {
    float z[NF];
    if (p == 0) {
      const float4* hp = (const float4*)(hpart + (size_t)n * NF);
#pragma unroll
      for (int j4 = 0; j4 < 8; ++j4) {
        float4 v = hp[j4];
        z[4 * j4] = v.x; z[4 * j4 + 1] = v.y; z[4 * j4 + 2] = v.z; z[4 * j4 + 3] = v.w;
      }
    } else {
      float dg = (float)(eo1 - eo0);
#pragma unroll
      for (int j = 0; j < NF; ++j) z[j] = dg * sW[B_VEC + j];
    }
#pragma unroll
    for (int k = 0; k < 8; ++k) {
      float v = s8[k];
      const float4* wr = (const float4*)(sW + W_NC + (8 * p + k) * NF);
#pragma unroll
      for (int j4 = 0; j4 < 8; ++j4) {
        float4 wv = wr[j4];
        z[4 * j4 + 0] = fmaf(v, wv.x, z[4 * j4 + 0]);
        z[4 * j4 + 1] = fmaf(v, wv.y, z[4 * j4 + 1]);
        z[4 * j4 + 2] = fmaf(v, wv.z, z[4 * j4 + 2]);
        z[4 * j4 + 3] = fmaf(v, wv.w, z[4 * j4 + 3]);
      }
    }
#pragma unroll
    for (int j = 0; j < NF; ++j) z[j] += __shfl_xor(z[j], 1, 64);
#pragma unroll
    for (int j = 0; j < NF; ++j) z[j] = sigmoidf_(z[j]);

    float pr[NF];
#pragma unroll
    for (int j = 0; j < NF; ++j) pr[j] = sW[B_SD + p * 32 + j];
    const float* wb = sW + W_SD + p * 1024;
    for (int k = 0; k < NF; ++k) {
      float v = z[k];
      const float4* wr = (const float4*)(wb + k * NF);
#pragma unroll
      for (int j4 = 0; j4 < 8; ++j4) {
        float4 wv = wr[j4];
        pr[4 * j4 + 0] = fmaf(v, wv.x, pr[4 * j4 + 0]);
        pr[4 * j4 + 1] = fmaf(v, wv.y, pr[4 * j4 + 1]);
        pr[4 * j4 + 2] = fmaf(v, wv.z, pr[4 * j4 + 2]);
        pr[4 * j4 + 3] = fmaf(v, wv.w, pr[4 * j4 + 3]);
      }
    }
    if (p == 0) {
      float4* a = (float4*)(PsW + (size_t)n * EF);
      a[0] = make_float4(pr[0], pr[1], pr[2], pr[3]);
      a[1] = make_float4(pr[4], pr[5], pr[6], pr[7]);
      a[2] = make_float4(pr[8], pr[9], pr[10], pr[11]);
      a[3] = make_float4(pr[12], pr[13], pr[14], pr[15]);
      float4* b = (float4*)(PdW + (size_t)n * EF);
      b[0] = make_float4(pr[16], pr[17], pr[18], pr[19]);
      b[1] = make_float4(pr[20], pr[21], pr[22], pr[23]);
      b[2] = make_float4(pr[24], pr[25], pr[26], pr[27]);
      b[3] = make_float4(pr[28], pr[29], pr[30], pr[31]);
    } else {
      float4* h = (float4*)(hpart + (size_t)n * NF);
#pragma unroll
      for (int j4 = 0; j4 < 8; ++j4)
        h[j4] = make_float4(pr[4 * j4], pr[4 * j4 + 1], pr[4 * j4 + 2], pr[4 * j4 + 3]);
    }
  }
}

// ---------------------------------------------------------------------------
// Final kernel = iteration 11 + node pass 12 + output head.
// seg(11) -> edge_11 (updates sE in LDS only) -> node_11 (registers) ->
// seg(12) -> node_12 fused with out = sig@Wnf + bnf.
// ---------------------------------------------------------------------------
__global__ void __launch_bounds__(TPB, 2) final_kernel(
    const float* __restrict__ e_buf,
    const unsigned short* __restrict__ src_s,
    const unsigned short* __restrict__ dst_s,
    const int* __restrict__ off, const int* __restrict__ bnd,
    const float* __restrict__ wbuf, const float* __restrict__ hpart,
    const float* __restrict__ PsR, const float* __restrict__ PdR,
    float* __restrict__ out) {
  __shared__ float sE[MAXE * EF];
  __shared__ float sW[WBUF_N];
  __shared__ unsigned short sSrc[MAXE];
  __shared__ unsigned short sDst[MAXE];
  const int tid = threadIdx.x, w = blockIdx.x;
  const int nstart = bnd[w], nend = bnd[w + 1];
  const int estart = off[nstart];
  const int eloc = off[nend] - estart;
  const int nloc = nend - nstart;

  for (int i = tid; i < WBUF_N; i += TPB) sW[i] = wbuf[i];
  {
    const float4* g4 = (const float4*)(e_buf + (size_t)estart * EF);
    float4* l4 = (float4*)sE;
    for (int i = tid; i < eloc * 4; i += TPB) l4[i] = g4[i];
    for (int i = tid; i < eloc; i += TPB) {
      sSrc[i] = src_s[estart + i];
      sDst[i] = dst_s[estart + i];
    }
  }
  const int ln = tid >> 1, p = tid & 1;
  const int n = nstart + ln;
  const bool active = (ln < nloc);
  int eo0 = 0, eo1 = 0;
  if (active) { eo0 = off[n] - estart; eo1 = off[n + 1] - estart; }
  const float dg = (float)(eo1 - eo0);
  __syncthreads();

  // seg(11)
  float s8a[8] = {0, 0, 0, 0, 0, 0, 0, 0};
  if (active) {
    for (int q = eo0; q < eo1; ++q) {
      const float4* ep = (const float4*)(sE + q * EF + 8 * p);
      float4 a = ep[0], b = ep[1];
      s8a[0] += a.x; s8a[1] += a.y; s8a[2] += a.z; s8a[3] += a.w;
      s8a[4] += b.x; s8a[5] += b.y; s8a[6] += b.z; s8a[7] += b.w;
    }
  }
  __syncthreads();   // seg reads done before edge phase rewrites sE

  // edge_11: update sE in LDS
  for (int q = tid; q < eloc; q += TPB) {
    int s = sSrc[q], d = sDst[q];
    const float4* ps = (const float4*)(PsR + (size_t)s * EF);
    const float4* pd = (const float4*)(PdR + (size_t)d * EF);
    float z[EF];
#pragma unroll
    for (int i4 = 0; i4 < 4; ++i4) {
      float4 a = ps[i4], b = pd[i4];
      z[4 * i4 + 0] = sW[B_COMB + 4 * i4 + 0] + a.x + b.x;
      z[4 * i4 + 1] = sW[B_COMB + 4 * i4 + 1] + a.y + b.y;
      z[4 * i4 + 2] = sW[B_COMB + 4 * i4 + 2] + a.z + b.z;
      z[4 * i4 + 3] = sW[B_COMB + 4 * i4 + 3] + a.w + b.w;
    }
    float4* ebp = (float4*)(sE + q * EF);
#pragma unroll
    for (int k4 = 0; k4 < 4; ++k4) {
      float4 ev = ebp[k4];
      float evv[4] = {ev.x, ev.y, ev.z, ev.w};
#pragma unroll
      for (int t = 0; t < 4; ++t) {
        float v = evv[t];
        const float4* wr = (const float4*)(sW + W_COMB + (4 * k4 + t) * EF);
#pragma unroll
        for (int i4 = 0; i4 < 4; ++i4) {
          float4 wv = wr[i4];
          z[4 * i4 + 0] = fmaf(v, wv.x, z[4 * i4 + 0]);
          z[4 * i4 + 1] = fmaf(v, wv.y, z[4 * i4 + 1]);
          z[4 * i4 + 2] = fmaf(v, wv.z, z[4 * i4 + 2]);
          z[4 * i4 + 3] = fmaf(v, wv.w, z[4 * i4 + 3]);
        }
      }
    }
#pragma unroll
    for (int i = 0; i < EF; ++i) z[i] = sigmoidf_(z[i]);
#pragma unroll
    for (int i4 = 0; i4 < 4; ++i4)
      ebp[i4] = make_float4(z[4 * i4], z[4 * i4 + 1], z[4 * i4 + 2], z[4 * i4 + 3]);
  }
  __syncthreads();   // e(12) visible in LDS

  if (!active) return;

  // seg(12)
  float s8b[8] = {0, 0, 0, 0, 0, 0, 0, 0};
  for (int q = eo0; q < eo1; ++q) {
    const float4* ep = (const float4*)(sE + q * EF + 8 * p);
    float4 a = ep[0], b = ep[1];
    s8b[0] += a.x; s8b[1] += a.y; s8b[2] += a.z; s8b[3] += a.w;
    s8b[4] += b.x; s8b[5] += b.y; s8b[6] += b.z; s8b[7] += b.w;
  }

  // node_11: z11 -> sig11 -> hpart(12) (both lanes compute W_NB projection)
  float z[NF];
  if (p == 0) {
    const float4* hp = (const float4*)(hpart + (size_t)n * NF);
#pragma unroll
    for (int j4 = 0; j4 < 8; ++j4) {
      float4 v = hp[j4];
      z[4 * j4] = v.x; z[4 * j4 + 1] = v.y; z[4 * j4 + 2] = v.z; z[4 * j4 + 3] = v.w;
    }
  } else {
#pragma unroll
    for (int j = 0; j < NF; ++j) z[j] = dg * sW[B_VEC + j];
  }
#pragma unroll
  for (int k = 0; k < 8; ++k) {
    float v = s8a[k];
    const float4* wr = (const float4*)(sW + W_NC + (8 * p + k) * NF);
#pragma unroll
    for (int j4 = 0; j4 < 8; ++j4) {
      float4 wv = wr[j4];
      z[4 * j4 + 0] = fmaf(v, wv.x, z[4 * j4 + 0]);
      z[4 * j4 + 1] = fmaf(v, wv.y, z[4 * j4 + 1]);
      z[4 * j4 + 2] = fmaf(v, wv.z, z[4 * j4 + 2]);
      z[4 * j4 + 3] = fmaf(v, wv.w, z[4 * j4 + 3]);
    }
  }
#pragma unroll
  for (int j = 0; j < NF; ++j) z[j] += __shfl_xor(z[j], 1, 64);
#pragma unroll
  for (int j = 0; j < NF; ++j) z[j] = sigmoidf_(z[j]);

  float h12[NF];   // hpart(12), computed identically on both lanes
#pragma unroll
  for (int j = 0; j < NF; ++j) h12[j] = sW[B_NB + j];
  for (int k = 0; k < NF; ++k) {
    float v = z[k];
    const float4* wr = (const float4*)(sW + W_NB + k * NF);
#pragma unroll
    for (int j4 = 0; j4 < 8; ++j4) {
      float4 wv = wr[j4];
      h12[4 * j4 + 0] = fmaf(v, wv.x, h12[4 * j4 + 0]);
      h12[4 * j4 + 1] = fmaf(v, wv.y, h12[4 * j4 + 1]);
      h12[4 * j4 + 2] = fmaf(v, wv.z, h12[4 * j4 + 2]);
      h12[4 * j4 + 3] = fmaf(v, wv.w, h12[4 * j4 + 3]);
    }
  }

  // node_12: z12 = h12 (p0) | dg*bvec (p1) + s8b@Wnc ; shfl-sum ; sigmoid
  float z2[NF];
  if (p == 0) {
#pragma unroll
    for (int j = 0; j < NF; ++j) z2[j] = h12[j];
  } else {
#pragma unroll
    for (int j = 0; j < NF; ++j) z2[j] = dg * sW[B_VEC + j];
  }
#pragma unroll
  for (int k = 0; k < 8; ++k) {
    float v = s8b[k];
    const float4* wr = (const float4*)(sW + W_NC + (8 * p + k) * NF);
#pragma unroll
    for (int j4 = 0; j4 < 8; ++j4) {
      float4 wv = wr[j4];
      z2[4 * j4 + 0] = fmaf(v, wv.x, z2[4 * j4 + 0]);
      z2[4 * j4 + 1] = fmaf(v, wv.y, z2[4 * j4 + 1]);
      z2[4 * j4 + 2] = fmaf(v, wv.z, z2[4 * j4 + 2]);
      z2[4 * j4 + 3] = fmaf(v, wv.w, z2[4 * j4 + 3]);
    }
  }
#pragma unroll
  for (int j = 0; j < NF; ++j) z2[j] += __shfl_xor(z2[j], 1, 64);
#pragma unroll
  for (int j = 0; j < NF; ++j) z2[j] = sigmoidf_(z2[j]);

  // output head: out = sig12 @ Wnf + bnf (split rows by lane, shfl-combine)
  float o[NC];
#pragma unroll
  for (int c = 0; c < NC; ++c) o[c] = (p == 0) ? sW[B_NF + c] : 0.0f;
  for (int k = 0; k < 16; ++k) {
    float v = z2[16 * p + k];
    const float* wr = sW + W_NF + (16 * p + k) * NC;
#pragma unroll
    for (int c = 0; c < NC; ++c) o[c] = fmaf(v, wr[c], o[c]);
  }
#pragma unroll
  for (int c = 0; c < NC; ++c) o[c] += __shfl_xor(o[c], 1, 64);
  if (p == 0) {
    float4* op = (float4*)(out + (size_t)n * NC);
    op[0] = make_float4(o[0], o[1], o[2], o[3]);
    op[1] = make_float4(o[4], o[5], o[6], o[7]);
  }
}

// ---------------------------------------------------------------------------
extern "C" void kernel_launch(void* const* d_in, const int* in_sizes, int n_in,
                              void* d_out, int out_size, void* d_ws, size_t ws_size,
                              hipStream_t stream) {
  const float* node_feat = (const float*)d_in[0];
  const float* edge_feat = (const float*)d_in[1];
  const int*   src = (const int*)d_in[2];
  const int*   dst = (const int*)d_in[3];
  const float* Wn  = (const float*)d_in[4];
  const float* bn  = (const float*)d_in[5];
  const float* We  = (const float*)d_in[6];
  const float* be  = (const float*)d_in[7];
  const float* Wem = (const float*)d_in[8];
  const float* bem = (const float*)d_in[9];
  const float* Wnm = (const float*)d_in[10];
  const float* bnm = (const float*)d_in[11];
  const float* Wfc = (const float*)d_in[12];
  const float* bfc = (const float*)d_in[13];
  float* out = (float*)d_out;

  float* ws    = (float*)d_ws;
  float* e_buf = ws;                                   // 3,840,000 f
  float* hpart = e_buf + (size_t)N_EDGES * EF;         //   960,000 f
  float* Ps0   = hpart + (size_t)N_NODES * NF;         //   480,000 f
  float* Ps1   = Ps0 + (size_t)N_NODES * EF;
  float* Pd0   = Ps1 + (size_t)N_NODES * EF;
  float* Pd1   = Pd0 + (size_t)N_NODES * EF;
  float* wbuf  = Pd1 + (size_t)N_NODES * EF;           //     4,096 f
  int* cnt     = (int*)(wbuf + 4096);                  //    30,000 i
  int* off     = cnt + N_NODES;                        //    30,001 i
  int* cursor  = off + N_NODES + 1;                    //    30,000 i
  int* bnd     = cursor + N_NODES;                     //  NWG+1 i
  unsigned short* src_s = (unsigned short*)(bnd + NWG + 1);     // 240,000 u16
  unsigned short* dst_s = src_s + N_EDGES;                      // 240,000 u16
  float* PsA[2] = {Ps0, Ps1};
  float* PdA[2] = {Pd0, Pd1};

  const int EB  = (N_EDGES + 255) / 256;       // 938
  const int NB2 = (2 * N_NODES + 255) / 256;   // 235

  // counting sort of edges by dst + partition + weight folding
  hipMemsetAsync(cnt, 0, (size_t)N_NODES * sizeof(int), stream);
  hist_kernel<<<EB, 256, 0, stream>>>(dst, cnt);
  scan_kernel<<<1, 1024, 0, stream>>>(cnt, off, cursor);
  scatter_kernel<<<EB, 256, 0, stream>>>(edge_feat, src, dst, cursor,
                                         src_s, dst_s, e_buf);
  partition_kernel<<<1, 1024, 0, stream>>>(off, bnd);
  precompute_kernel<<<1, 256, 0, stream>>>(Wn, bn, We, be, Wem, bem,
                                           Wnm, bnm, Wfc, bfc, wbuf);
  init_proj_kernel<<<NB2, 256, 0, stream>>>(node_feat, wbuf, Ps1, Pd1, hpart);

  // iterations 1..10 fused (node_i + edge_i per kernel); 11 + node_12 + head
  // in final_kernel. P ping-pong: iter i reads P[i&1], writes P[(i+1)&1].
  for (int i = 1; i <= 10; ++i) {
    iter_kernel<<<NWG, TPB, 0, stream>>>(
        e_buf, src_s, dst_s, off, bnd, wbuf, hpart,
        PsA[i & 1], PdA[i & 1], PsA[(i + 1) & 1], PdA[(i + 1) & 1]);
  }
  final_kernel<<<NWG, TPB, 0, stream>>>(
      e_buf, src_s, dst_s, off, bnd, wbuf, hpart, PsA[1], PdA[1], out);
}

// Round 6
// 773.267 us; speedup vs baseline: 1.0167x; 1.0167x over previous
//
#include <hip/hip_runtime.h>

#define N_NODES 30000
#define N_EDGES 240000
#define NF 32
#define EF 16
#define HF 64
#define NC 8
#define NWG 512
#define TPB 256

// wbuf layout (float offsets)
#define W_COMB 0      // [16][16] We @ Wem[64:128)
#define B_COMB 256    // [16]     bem + be@Wem[64:128)
#define W_NC   272    // [16][32] We @ Wnm[0:64)
#define B_VEC  784    // [32]     be @ Wnm[0:64)
#define W_SD   816    // [32][32] cols 0-15: Wn@Wem[0:64) ; cols 16-31: Wn@Wem[128:192)
#define W_NB   1840   // [32][32] Wn @ Wnm[64:128)   (== W_SD + 1024)
#define B_SD   2864   // [32]     [bn@WemS | bn@WemD]
#define B_NB   2896   // [32]     bnm + bn@Wnm[64:128)  (== B_SD + 32)
#define W_NF   2928   // [32][8]  Wn @ Wfc
#define B_NF   3184   // [8]      bfc + bn@Wfc
#define WBUF_N 3192

__device__ __forceinline__ float sigmoidf_(float x) {
  return 1.0f / (1.0f + __expf(-x));
}

// ---------------------------------------------------------------------------
__global__ void __launch_bounds__(256) hist_kernel(
    const int* __restrict__ dst, int* __restrict__ cnt) {
  int e = blockIdx.x * 256 + threadIdx.x;
  if (e < N_EDGES) atomicAdd(&cnt[dst[e]], 1);
}

// exclusive scan of cnt[30000] -> off[30001], cursor = copy of off
__global__ void __launch_bounds__(1024) scan_kernel(
    const int* __restrict__ cnt, int* __restrict__ off, int* __restrict__ cursor) {
  __shared__ int part[1024];
  int t = threadIdx.x;
  const int CH = (N_NODES + 1023) / 1024;   // 30
  int base = t * CH;
  int lc[CH];
  int sum = 0;
  for (int i = 0; i < CH; ++i) {
    int idx = base + i;
    lc[i] = (idx < N_NODES) ? cnt[idx] : 0;
    sum += lc[i];
  }
  part[t] = sum;
  __syncthreads();
  for (int ofs = 1; ofs < 1024; ofs <<= 1) {
    int v = (t >= ofs) ? part[t - ofs] : 0;
    __syncthreads();
    part[t] += v;
    __syncthreads();
  }
  int run = (t == 0) ? 0 : part[t - 1];
  for (int i = 0; i < CH; ++i) {
    int idx = base + i;
    if (idx < N_NODES) {
      off[idx] = run;
      cursor[idx] = run;
      run += lc[i];
    }
  }
  if (t == 1023) off[N_NODES] = part[1023];
}

__global__ void __launch_bounds__(256) scatter_kernel(
    const float* __restrict__ edge_feat, const int* __restrict__ src,
    const int* __restrict__ dst, int* __restrict__ cursor,
    unsigned short* __restrict__ src_s, unsigned short* __restrict__ dst_s,
    float* __restrict__ e_buf) {
  int e = blockIdx.x * 256 + threadIdx.x;
  if (e >= N_EDGES) return;
  int d = dst[e];
  int pos = atomicAdd(&cursor[d], 1);
  src_s[pos] = (unsigned short)src[e];
  dst_s[pos] = (unsigned short)d;
  const float4* ep = (const float4*)(edge_feat + (size_t)e * EF);
  float4* op = (float4*)(e_buf + (size_t)pos * EF);
  op[0] = ep[0]; op[1] = ep[1]; op[2] = ep[2]; op[3] = ep[3];
}

// bnd[w] = smallest n with off[n] >= w*E/NWG ; bnd[NWG] = N
__global__ void __launch_bounds__(1024) partition_kernel(
    const int* __restrict__ off, int* __restrict__ bnd) {
  for (int w = threadIdx.x; w <= NWG; w += 1024) {
    if (w == NWG) { bnd[w] = N_NODES; continue; }
    long long target = ((long long)w * N_EDGES) / NWG;
    int lo = 0, hi = N_NODES;
    while (lo < hi) {
      int mid = (lo + hi) >> 1;
      if ((long long)off[mid] < target) lo = mid + 1; else hi = mid;
    }
    bnd[w] = lo;
  }
}

// ---------------------------------------------------------------------------
__global__ void __launch_bounds__(256) precompute_kernel(
    const float* __restrict__ Wn, const float* __restrict__ bn,
    const float* __restrict__ We, const float* __restrict__ be,
    const float* __restrict__ Wem, const float* __restrict__ bem,
    const float* __restrict__ Wnm, const float* __restrict__ bnm,
    const float* __restrict__ Wfc, const float* __restrict__ bfc,
    float* __restrict__ wbuf) {
  int tid = threadIdx.x;
  {  // Wcomb
    int r = tid >> 4, c = tid & 15;
    float acc = 0.f;
    for (int j = 0; j < HF; ++j) acc = fmaf(We[r * HF + j], Wem[(HF + j) * EF + c], acc);
    wbuf[W_COMB + tid] = acc;
  }
  for (int idx = tid; idx < EF * NF; idx += 256) {  // Wnc
    int r = idx >> 5, c = idx & 31;
    float acc = 0.f;
    for (int j = 0; j < HF; ++j) acc = fmaf(We[r * HF + j], Wnm[j * NF + c], acc);
    wbuf[W_NC + idx] = acc;
  }
  for (int idx = tid; idx < NF * NF; idx += 256) {  // WSD
    int r = idx >> 5, c = idx & 31;
    float acc = 0.f;
    if (c < EF) {
      for (int j = 0; j < HF; ++j) acc = fmaf(Wn[r * HF + j], Wem[j * EF + c], acc);
    } else {
      int cc = c - EF;
      for (int j = 0; j < HF; ++j) acc = fmaf(Wn[r * HF + j], Wem[(2 * HF + j) * EF + cc], acc);
    }
    wbuf[W_SD + idx] = acc;
  }
  for (int idx = tid; idx < NF * NF; idx += 256) {  // WnB
    int r = idx >> 5, c = idx & 31;
    float acc = 0.f;
    for (int j = 0; j < HF; ++j) acc = fmaf(Wn[r * HF + j], Wnm[(HF + j) * NF + c], acc);
    wbuf[W_NB + idx] = acc;
  }
  if (tid < NF * NC) {  // Wnf
    int r = tid >> 3, c = tid & 7;
    float acc = 0.f;
    for (int j = 0; j < HF; ++j) acc = fmaf(Wn[r * HF + j], Wfc[j * NC + c], acc);
    wbuf[W_NF + tid] = acc;
  }
  if (tid < EF) {  // bcomb
    float acc = bem[tid];
    for (int j = 0; j < HF; ++j) acc = fmaf(be[j], Wem[(HF + j) * EF + tid], acc);
    wbuf[B_COMB + tid] = acc;
  }
  if (tid < NF) {  // bvec
    float acc = 0.f;
    for (int j = 0; j < HF; ++j) acc = fmaf(be[j], Wnm[j * NF + tid], acc);
    wbuf[B_VEC + tid] = acc;
  }
  if (tid < NF) {  // bSD
    float acc = 0.f;
    if (tid < EF) {
      for (int j = 0; j < HF; ++j) acc = fmaf(bn[j], Wem[j * EF + tid], acc);
    } else {
      int cc = tid - EF;
      for (int j = 0; j < HF; ++j) acc = fmaf(bn[j], Wem[(2 * HF + j) * EF + cc], acc);
    }
    wbuf[B_SD + tid] = acc;
  }
  if (tid < NF) {  // bNB
    float acc = bnm[tid];
    for (int j = 0; j < HF; ++j) acc = fmaf(bn[j], Wnm[(HF + j) * NF + tid], acc);
    wbuf[B_NB + tid] = acc;
  }
  if (tid < NC) {  // bnf
    float acc = bfc[tid];
    for (int j = 0; j < HF; ++j) acc = fmaf(bn[j], Wfc[j * NC + tid], acc);
    wbuf[B_NF + tid] = acc;
  }
}

// ---------------------------------------------------------------------------
// init: [P_s|P_d] = x@WSD + bSD (p=0) ; hpart = x@WnB + bNB (p=1)
// ---------------------------------------------------------------------------
__global__ void __launch_bounds__(256) init_proj_kernel(
    const float* __restrict__ node_feat, const float* __restrict__ wbuf,
    float* __restrict__ Ps, float* __restrict__ Pd, float* __restrict__ hpart) {
  __shared__ float sPRJ[2048];
  __shared__ float sPB[64];
  for (int i = threadIdx.x; i < 2048; i += 256) sPRJ[i] = wbuf[W_SD + i];
  if (threadIdx.x < 64) sPB[threadIdx.x] = wbuf[B_SD + threadIdx.x];
  __syncthreads();
  int gid = blockIdx.x * 256 + threadIdx.x;
  int n = gid >> 1, p = gid & 1;
  if (n >= N_NODES) return;
  float x[NF];
  const float4* xp = (const float4*)(node_feat + (size_t)n * NF);
#pragma unroll
  for (int k4 = 0; k4 < 8; ++k4) {
    float4 v = xp[k4];
    x[4 * k4] = v.x; x[4 * k4 + 1] = v.y; x[4 * k4 + 2] = v.z; x[4 * k4 + 3] = v.w;
  }
  float pr[NF];
  const float* pb = sPB + p * 32;
#pragma unroll
  for (int j = 0; j < NF; ++j) pr[j] = pb[j];
  const float* wbase = sPRJ + p * 1024;
  for (int k = 0; k < NF; ++k) {
    float v = x[k];
    const float4* wr = (const float4*)(wbase + k * NF);
#pragma unroll
    for (int j4 = 0; j4 < 8; ++j4) {
      float4 w = wr[j4];
      pr[4 * j4 + 0] = fmaf(v, w.x, pr[4 * j4 + 0]);
      pr[4 * j4 + 1] = fmaf(v, w.y, pr[4 * j4 + 1]);
      pr[4 * j4 + 2] = fmaf(v, w.z, pr[4 * j4 + 2]);
      pr[4 * j4 + 3] = fmaf(v, w.w, pr[4 * j4 + 3]);
    }
  }
  if (p == 0) {
    float4* a = (float4*)(Ps + (size_t)n * EF);
    a[0] = make_float4(pr[0], pr[1], pr[2], pr[3]);
    a[1] = make_float4(pr[4], pr[5], pr[6], pr[7]);
    a[2] = make_float4(pr[8], pr[9], pr[10], pr[11]);
    a[3] = make_float4(pr[12], pr[13], pr[14], pr[15]);
    float4* b = (float4*)(Pd + (size_t)n * EF);
    b[0] = make_float4(pr[16], pr[17], pr[18], pr[19]);
    b[1] = make_float4(pr[20], pr[21], pr[22], pr[23]);
    b[2] = make_float4(pr[24], pr[25], pr[26], pr[27]);
    b[3] = make_float4(pr[28], pr[29], pr[30], pr[31]);
  } else {
    float4* h = (float4*)(hpart + (size_t)n * NF);
#pragma unroll
    for (int j4 = 0; j4 < 8; ++j4)
      h[j4] = make_float4(pr[4 * j4], pr[4 * j4 + 1], pr[4 * j4 + 2], pr[4 * j4 + 3]);
  }
}

// ---------------------------------------------------------------------------
// Fused iteration i (1..11): WG w owns nodes [bnd[w],bnd[w+1]) and their
// dst-sorted edge slice. Node phase (seg+update fused, 2 lanes/node) reads
// e(i) from global; sync; edge phase overwrites the slice with e(i+1).
// No LDS edge staging (no bank conflicts), no register cap (no spills).
// Cross-WG visibility via kernel boundary; slices are disjoint -> no races.
// ---------------------------------------------------------------------------
__global__ void __launch_bounds__(TPB) iter_kernel(
    float* __restrict__ e_buf,
    const unsigned short* __restrict__ src_s,
    const unsigned short* __restrict__ dst_s,
    const int* __restrict__ off, const int* __restrict__ bnd,
    const float* __restrict__ wbuf, float* __restrict__ hpart,
    const float* __restrict__ PsR, const float* __restrict__ PdR,
    float* __restrict__ PsW, float* __restrict__ PdW) {
  __shared__ float sW[WBUF_N];              // 12.8 KB
  const int tid = threadIdx.x, w = blockIdx.x;
  const int nstart = bnd[w], nend = bnd[w + 1];
  const int estart = off[nstart];
  const int eloc = off[nend] - estart;
  const int nloc = nend - nstart;
  for (int i = tid; i < WBUF_N; i += TPB) sW[i] = wbuf[i];
  __syncthreads();

  // ---- node phase: 2 lanes per node, dynamic loop over owned nodes ----
  const int p = tid & 1;
  for (int ln = tid >> 1; ln < nloc; ln += TPB / 2) {
    const int n = nstart + ln;
    const int o0 = off[n], o1 = off[n + 1];
    float s8[8] = {0, 0, 0, 0, 0, 0, 0, 0};
    for (int q = o0; q < o1; ++q) {
      const float4* ep = (const float4*)(e_buf + (size_t)q * EF + 8 * p);
      float4 a = ep[0], b = ep[1];
      s8[0] += a.x; s8[1] += a.y; s8[2] += a.z; s8[3] += a.w;
      s8[4] += b.x; s8[5] += b.y; s8[6] += b.z; s8[7] += b.w;
    }
    float z[NF];
    if (p == 0) {
      const float4* hp = (const float4*)(hpart + (size_t)n * NF);
#pragma unroll
      for (int j4 = 0; j4 < 8; ++j4) {
        float4 v = hp[j4];
        z[4 * j4] = v.x; z[4 * j4 + 1] = v.y; z[4 * j4 + 2] = v.z; z[4 * j4 + 3] = v.w;
      }
    } else {
      float dg = (float)(o1 - o0);
#pragma unroll
      for (int j = 0; j < NF; ++j) z[j] = dg * sW[B_VEC + j];
    }
#pragma unroll
    for (int k = 0; k < 8; ++k) {
      float v = s8[k];
      const float4* wr = (const float4*)(sW + W_NC + (8 * p + k) * NF);
#pragma unroll
      for (int j4 = 0; j4 < 8; ++j4) {
        float4 wv = wr[j4];
        z[4 * j4 + 0] = fmaf(v, wv.x, z[4 * j4 + 0]);
        z[4 * j4 + 1] = fmaf(v, wv.y, z[4 * j4 + 1]);
        z[4 * j4 + 2] = fmaf(v, wv.z, z[4 * j4 + 2]);
        z[4 * j4 + 3] = fmaf(v, wv.w, z[4 * j4 + 3]);
      }
    }
    // pair exchange (lanes tid, tid^1 share ln -> lockstep), then sigmoid
#pragma unroll
    for (int j = 0; j < NF; ++j) z[j] += __shfl_xor(z[j], 1, 64);
#pragma unroll
    for (int j = 0; j < NF; ++j) z[j] = sigmoidf_(z[j]);

    float pr[NF];
#pragma unroll
    for (int j = 0; j < NF; ++j) pr[j] = sW[B_SD + p * 32 + j];
    const float* wb = sW + W_SD + p * 1024;   // p=0: WSD -> Ps|Pd ; p=1: WnB -> hpart
    for (int k = 0; k < NF; ++k) {
      float v = z[k];
      const float4* wr = (const float4*)(wb + k * NF);
#pragma unroll
      for (int j4 = 0; j4 < 8; ++j4) {
        float4 wv = wr[j4];
        pr[4 * j4 + 0] = fmaf(v, wv.x, pr[4 * j4 + 0]);
        pr[4 * j4 + 1] = fmaf(v, wv.y, pr[4 * j4 + 1]);
        pr[4 * j4 + 2] = fmaf(v, wv.z, pr[4 * j4 + 2]);
        pr[4 * j4 + 3] = fmaf(v, wv.w, pr[4 * j4 + 3]);
      }
    }
    if (p == 0) {
      float4* a = (float4*)(PsW + (size_t)n * EF);
      a[0] = make_float4(pr[0], pr[1], pr[2], pr[3]);
      a[1] = make_float4(pr[4], pr[5], pr[6], pr[7]);
      a[2] = make_float4(pr[8], pr[9], pr[10], pr[11]);
      a[3] = make_float4(pr[12], pr[13], pr[14], pr[15]);
      float4* b = (float4*)(PdW + (size_t)n * EF);
      b[0] = make_float4(pr[16], pr[17], pr[18], pr[19]);
      b[1] = make_float4(pr[20], pr[21], pr[22], pr[23]);
      b[2] = make_float4(pr[24], pr[25], pr[26], pr[27]);
      b[3] = make_float4(pr[28], pr[29], pr[30], pr[31]);
    } else {
      float4* h = (float4*)(hpart + (size_t)n * NF);
#pragma unroll
      for (int j4 = 0; j4 < 8; ++j4)
        h[j4] = make_float4(pr[4 * j4], pr[4 * j4 + 1], pr[4 * j4 + 2], pr[4 * j4 + 3]);
    }
  }
  __syncthreads();   // all node-phase reads of e(i) slice complete

  // ---- edge phase: e' = sigmoid(bcomb + e@Wcomb + Ps[src] + Pd[dst]) ----
  for (int q = tid; q < eloc; q += TPB) {
    const int qe = estart + q;
    const int s = src_s[qe], d = dst_s[qe];
    const float4* ps = (const float4*)(PsR + (size_t)s * EF);
    const float4* pd = (const float4*)(PdR + (size_t)d * EF);
    float z[EF];
#pragma unroll
    for (int i4 = 0; i4 < 4; ++i4) {
      float4 a = ps[i4], b = pd[i4];
      z[4 * i4 + 0] = sW[B_COMB + 4 * i4 + 0] + a.x + b.x;
      z[4 * i4 + 1] = sW[B_COMB + 4 * i4 + 1] + a.y + b.y;
      z[4 * i4 + 2] = sW[B_COMB + 4 * i4 + 2] + a.z + b.z;
      z[4 * i4 + 3] = sW[B_COMB + 4 * i4 + 3] + a.w + b.w;
    }
    float4* ebp = (float4*)(e_buf + (size_t)qe * EF);
#pragma unroll
    for (int k4 = 0; k4 < 4; ++k4) {
      float4 ev = ebp[k4];
      float evv[4] = {ev.x, ev.y, ev.z, ev.w};
#pragma unroll
      for (int t = 0; t < 4; ++t) {
        float v = evv[t];
        const float4* wr = (const float4*)(sW + W_COMB + (4 * k4 + t) * EF);
#pragma unroll
        for (int i4 = 0; i4 < 4; ++i4) {
          float4 wv = wr[i4];
          z[4 * i4 + 0] = fmaf(v, wv.x, z[4 * i4 + 0]);
          z[4 * i4 + 1] = fmaf(v, wv.y, z[4 * i4 + 1]);
          z[4 * i4 + 2] = fmaf(v, wv.z, z[4 * i4 + 2]);
          z[4 * i4 + 3] = fmaf(v, wv.w, z[4 * i4 + 3]);
        }
      }
    }
#pragma unroll
    for (int i = 0; i < EF; ++i) z[i] = sigmoidf_(z[i]);
#pragma unroll
    for (int i4 = 0; i4 < 4; ++i4)
      ebp[i4] = make_float4(z[4 * i4], z[4 * i4 + 1], z[4 * i4 + 2], z[4 * i4 + 3]);
  }
}

// ---------------------------------------------------------------------------
// Final: node pass 12 + output head. Grid-wide 2 threads/node; reads e(12).
// ---------------------------------------------------------------------------
__global__ void __launch_bounds__(256) final12_kernel(
    const float* __restrict__ e_buf, const float* __restrict__ hpart,
    const int* __restrict__ off, const float* __restrict__ wbuf,
    float* __restrict__ out) {
  __shared__ float sW[WBUF_N];
  for (int i = threadIdx.x; i < WBUF_N; i += 256) sW[i] = wbuf[i];
  __syncthreads();
  int gid = blockIdx.x * 256 + threadIdx.x;
  int n = gid >> 1, p = gid & 1;
  if (n >= N_NODES) return;
  int o0 = off[n], o1 = off[n + 1];

  float s8[8] = {0, 0, 0, 0, 0, 0, 0, 0};
  for (int q = o0; q < o1; ++q) {
    const float4* ep = (const float4*)(e_buf + (size_t)q * EF + 8 * p);
    float4 a = ep[0], b = ep[1];
    s8[0] += a.x; s8[1] += a.y; s8[2] += a.z; s8[3] += a.w;
    s8[4] += b.x; s8[5] += b.y; s8[6] += b.z; s8[7] += b.w;
  }
  float z[NF];
  if (p == 0) {
    const float4* hp = (const float4*)(hpart + (size_t)n * NF);
#pragma unroll
    for (int j4 = 0; j4 < 8; ++j4) {
      float4 v = hp[j4];
      z[4 * j4] = v.x; z[4 * j4 + 1] = v.y; z[4 * j4 + 2] = v.z; z[4 * j4 + 3] = v.w;
    }
  } else {
    float dg = (float)(o1 - o0);
#pragma unroll
    for (int j = 0; j < NF; ++j) z[j] = dg * sW[B_VEC + j];
  }
#pragma unroll
  for (int k = 0; k < 8; ++k) {
    float v = s8[k];
    const float4* wr = (const float4*)(sW + W_NC + (8 * p + k) * NF);
#pragma unroll
    for (int j4 = 0; j4 < 8; ++j4) {
      float4 wv = wr[j4];
      z[4 * j4 + 0] = fmaf(v, wv.x, z[4 * j4 + 0]);
      z[4 * j4 + 1] = fmaf(v, wv.y, z[4 * j4 + 1]);
      z[4 * j4 + 2] = fmaf(v, wv.z, z[4 * j4 + 2]);
      z[4 * j4 + 3] = fmaf(v, wv.w, z[4 * j4 + 3]);
    }
  }
#pragma unroll
  for (int j = 0; j < NF; ++j) z[j] += __shfl_xor(z[j], 1, 64);
#pragma unroll
  for (int j = 0; j < NF; ++j) z[j] = sigmoidf_(z[j]);

  // head: out = sig @ Wnf + bnf; each lane does its 16 rows. NOTE: constant
  // VGPR-array indices in both select arms (dynamic indexing would spill).
  float o[NC];
#pragma unroll
  for (int c = 0; c < NC; ++c) o[c] = (p == 0) ? sW[B_NF + c] : 0.0f;
#pragma unroll
  for (int k = 0; k < 16; ++k) {
    float v = (p == 0) ? z[k] : z[16 + k];
    const float* wr = sW + W_NF + (16 * p + k) * NC;
#pragma unroll
    for (int c = 0; c < NC; ++c) o[c] = fmaf(v, wr[c], o[c]);
  }
#pragma unroll
  for (int c = 0; c < NC; ++c) o[c] += __shfl_xor(o[c], 1, 64);
  if (p == 0) {
    float4* op = (float4*)(out + (size_t)n * NC);
    op[0] = make_float4(o[0], o[1], o[2], o[3]);
    op[1] = make_float4(o[4], o[5], o[6], o[7]);
  }
}

// ---------------------------------------------------------------------------
extern "C" void kernel_launch(void* const* d_in, const int* in_sizes, int n_in,
                              void* d_out, int out_size, void* d_ws, size_t ws_size,
                              hipStream_t stream) {
  const float* node_feat = (const float*)d_in[0];
  const float* edge_feat = (const float*)d_in[1];
  const int*   src = (const int*)d_in[2];
  const int*   dst = (const int*)d_in[3];
  const float* Wn  = (const float*)d_in[4];
  const float* bn  = (const float*)d_in[5];
  const float* We  = (const float*)d_in[6];
  const float* be  = (const float*)d_in[7];
  const float* Wem = (const float*)d_in[8];
  const float* bem = (const float*)d_in[9];
  const float* Wnm = (const float*)d_in[10];
  const float* bnm = (const float*)d_in[11];
  const float* Wfc = (const float*)d_in[12];
  const float* bfc = (const float*)d_in[13];
  float* out = (float*)d_out;

  float* ws    = (float*)d_ws;
  float* e_buf = ws;                                   // 3,840,000 f
  float* hpart = e_buf + (size_t)N_EDGES * EF;         //   960,000 f
  float* Ps0   = hpart + (size_t)N_NODES * NF;         //   480,000 f
  float* Ps1   = Ps0 + (size_t)N_NODES * EF;
  float* Pd0   = Ps1 + (size_t)N_NODES * EF;
  float* Pd1   = Pd0 + (size_t)N_NODES * EF;
  float* wbuf  = Pd1 + (size_t)N_NODES * EF;           //     4,096 f
  int* cnt     = (int*)(wbuf + 4096);                  //    30,000 i
  int* off     = cnt + N_NODES;                        //    30,001 i
  int* cursor  = off + N_NODES + 1;                    //    30,000 i
  int* bnd     = cursor + N_NODES;                     //  NWG+1 i
  unsigned short* src_s = (unsigned short*)(bnd + NWG + 1);     // 240,000 u16
  unsigned short* dst_s = src_s + N_EDGES;                      // 240,000 u16
  float* PsA[2] = {Ps0, Ps1};
  float* PdA[2] = {Pd0, Pd1};

  const int EB  = (N_EDGES + 255) / 256;       // 938
  const int NB2 = (2 * N_NODES + 255) / 256;   // 235

  // counting sort of edges by dst + partition + weight folding
  hipMemsetAsync(cnt, 0, (size_t)N_NODES * sizeof(int), stream);
  hist_kernel<<<EB, 256, 0, stream>>>(dst, cnt);
  scan_kernel<<<1, 1024, 0, stream>>>(cnt, off, cursor);
  scatter_kernel<<<EB, 256, 0, stream>>>(edge_feat, src, dst, cursor,
                                         src_s, dst_s, e_buf);
  partition_kernel<<<1, 1024, 0, stream>>>(off, bnd);
  precompute_kernel<<<1, 256, 0, stream>>>(Wn, bn, We, be, Wem, bem,
                                           Wnm, bnm, Wfc, bfc, wbuf);
  init_proj_kernel<<<NB2, 256, 0, stream>>>(node_feat, wbuf, Ps1, Pd1, hpart);

  // iterations 1..11: fused node_i (seg of e(i) + projections for i+1) and
  // edge_i (e(i) -> e(i+1)). P ping-pong: iter i reads P[i&1], writes
  // P[(i+1)&1]. Then node pass 12 + output head.
  for (int i = 1; i <= 11; ++i) {
    iter_kernel<<<NWG, TPB, 0, stream>>>(
        e_buf, src_s, dst_s, off, bnd, wbuf, hpart,
        PsA[i & 1], PdA[i & 1], PsA[(i + 1) & 1], PdA[(i + 1) & 1]);
  }
  final12_kernel<<<NB2, 256, 0, stream>>>(e_buf, hpart, off, wbuf, out);
}